// Round 7
// baseline (445.905 us; speedup 1.0000x reference)
//
#include <hip/hip_runtime.h>
#include <hip/hip_bf16.h>

#define DEV __device__ __forceinline__

constexpr int N = 65536;
constexpr int C = 768;
constexpr int T = 64;

using bf16 = __hip_bfloat16;
using short8 = __attribute__((ext_vector_type(8))) short;
using f32x4  = __attribute__((ext_vector_type(4))) float;

DEV ushort f2bits(float v) { union { __hip_bfloat16 h; ushort u; } x; x.h = __float2bfloat16(v); return x.u; }
DEV float bits2f(ushort b) { union { uint u; float f; } x; x.u = ((uint)b) << 16; return x.f; }
DEV f32x4 mfma16(short8 a, short8 b, f32x4 c) { return __builtin_amdgcn_mfma_f32_16x16x32_bf16(a, b, c, 0, 0, 0); }
// XOR swizzle: 16B-unit permutation within a 128B (64-short) row. Bijective per row.
DEV int swz(int row, int col) { return row * 64 + (col ^ ((row & 7) << 3)); }

DEV float wredsum(float v) {
#pragma unroll
  for (int o = 32; o > 0; o >>= 1) v += __shfl_xor(v, o, 64);
  return v;
}

// ---------------------------------------------------------------------------
// K0: pack w1/w2/wf into MFMA-fragment-ordered bf16 arrays, zero-padded K 48->64.
// frag f = (g*NT + tile)*2 + ktile; element [f*512 + lane*8 + j]
//   = W[row = tile*16 + (lane&15)][k = ktile*32 + ((lane>>4)&3)*8 + j]
// ---------------------------------------------------------------------------
__global__ __launch_bounds__(256) void k_wprep(const float* __restrict__ w1,
                                               const float* __restrict__ w2,
                                               const float* __restrict__ wf,
                                               short* __restrict__ w1p,
                                               short* __restrict__ w2p,
                                               short* __restrict__ wfp) {
  const int b = blockIdx.x, tid = threadIdx.x;
  if (b < 192) {            // w1p: 16 g * 3 ot * 2 kt * 512 = 49152
    int idx = b * 256 + tid;
    int j = idx & 7, lane = (idx >> 3) & 63, u = idx >> 9;
    int kt = u & 1, v = u >> 1, ot = v % 3, g = v / 3;
    int o = ot * 16 + (lane & 15), k = kt * 32 + ((lane >> 4) & 3) * 8 + j;
    w1p[idx] = (k < 48) ? (short)f2bits(w1[g * 2304 + o * 48 + k]) : (short)0;
  } else if (b < 448) {     // w2p: 16 g * 4 tt * 2 kt * 512 = 65536
    int idx = (b - 192) * 256 + tid;
    int j = idx & 7, lane = (idx >> 3) & 63, u = idx >> 9;
    int kt = u & 1, v = u >> 1, tt = v & 3, g = v >> 2;
    int t = tt * 16 + (lane & 15), k = kt * 32 + ((lane >> 4) & 3) * 8 + j;
    w2p[idx] = (k < 48) ? (short)f2bits(w2[t * 768 + g * 48 + k]) : (short)0;
  } else {                  // wfp: like w1p
    int idx = (b - 448) * 256 + tid;
    int j = idx & 7, lane = (idx >> 3) & 63, u = idx >> 9;
    int kt = u & 1, v = u >> 1, ot = v % 3, g = v / 3;
    int o = ot * 16 + (lane & 15), k = kt * 32 + ((lane >> 4) & 3) * 8 + j;
    wfp[idx] = (k < 48) ? (short)f2bits(wf[g * 2304 + o * 48 + k]) : (short)0;
  }
}

// ---------------------------------------------------------------------------
// K1: LayerNorm rows of x -> xn (bf16) + pooled sums. Single-pass moments.
// ---------------------------------------------------------------------------
__global__ __launch_bounds__(256, 4) void k_ln(const float4* __restrict__ x,
                                               const float4* __restrict__ gam,
                                               const float4* __restrict__ bet,
                                               uint2* __restrict__ xn,
                                               float* __restrict__ pooled) {
  const int tid = threadIdx.x, wave = tid >> 6, lane = tid & 63;
  float4 gg[3], bb[3], pool[3];
#pragma unroll
  for (int j = 0; j < 3; j++) {
    gg[j] = gam[lane + 64 * j]; bb[j] = bet[lane + 64 * j];
    pool[j] = make_float4(0.f, 0.f, 0.f, 0.f);
  }
  const int r0 = (blockIdx.x * 4 + wave) * 16;
  for (int r = r0; r < r0 + 16; ++r) {
    const float4* xr = x + (size_t)r * 192;
    float4 v[3]; float s = 0.f, q = 0.f;
#pragma unroll
    for (int j = 0; j < 3; j++) {
      v[j] = xr[lane + 64 * j];
      s += v[j].x + v[j].y + v[j].z + v[j].w;
      q += v[j].x * v[j].x + v[j].y * v[j].y + v[j].z * v[j].z + v[j].w * v[j].w;
    }
    s = wredsum(s); q = wredsum(q);
    const float mu = s * (1.f / C);
    const float rs = rsqrtf(q * (1.f / C) - mu * mu + 1e-5f);
    uint2* xo = xn + (size_t)r * 192;
#pragma unroll
    for (int j = 0; j < 3; j++) {
      float y0 = (v[j].x - mu) * rs * gg[j].x + bb[j].x;
      float y1 = (v[j].y - mu) * rs * gg[j].y + bb[j].y;
      float y2 = (v[j].z - mu) * rs * gg[j].z + bb[j].z;
      float y3 = (v[j].w - mu) * rs * gg[j].w + bb[j].w;
      pool[j].x += y0; pool[j].y += y1; pool[j].z += y2; pool[j].w += y3;
      xo[lane + 64 * j] = make_uint2((uint)f2bits(y0) | ((uint)f2bits(y1) << 16),
                                     (uint)f2bits(y2) | ((uint)f2bits(y3) << 16));
    }
  }
  __shared__ float lp[4][C];
#pragma unroll
  for (int j = 0; j < 3; j++) {
    int base = (lane + 64 * j) * 4;
    lp[wave][base] = pool[j].x; lp[wave][base + 1] = pool[j].y;
    lp[wave][base + 2] = pool[j].z; lp[wave][base + 3] = pool[j].w;
  }
  __syncthreads();
  for (int c = tid; c < C; c += 256)
    atomicAdd(&pooled[c], lp[0][c] + lp[1][c] + lp[2][c] + lp[3][c]);
}

// ---------------------------------------------------------------------------
// K2: pooled -> ratio -> num_tokens
// ---------------------------------------------------------------------------
__global__ __launch_bounds__(256) void k_pool(const float* __restrict__ pooled,
                                              const float* __restrict__ pw,
                                              const float* __restrict__ pb,
                                              int* __restrict__ ntok) {
  const int tid = threadIdx.x, wave = tid >> 6, lane = tid & 63;
  float a = 0.f;
  for (int c = tid; c < C; c += 256) a += pooled[c] * (1.f / N) * pw[c];
  a = wredsum(a);
  __shared__ float red[4];
  if (lane == 0) red[wave] = a;
  __syncthreads();
  if (tid == 0) {
    float d = red[0] + red[1] + red[2] + red[3] + pb[0];
    float ratio = 1.f / (1.f + expf(-d));
    int nt = (int)floorf(ratio * 64.f);
    nt = nt < 0 ? 0 : (nt > 64 ? 64 : nt);
    *ntok = nt;
  }
}

// ---------------------------------------------------------------------------
// K3 (MFMA): fused grouped conv1 + ReLU + scores GEMM + per-block softmax
// partials. Per-wave double-buffered h (g&1); fragment-ordered weights from
// global (L1/L2-hot). Epilogue: in-block (m, sumexp) per t -> part2[t][blk].
// ---------------------------------------------------------------------------
__global__ __launch_bounds__(256, 4) void k_cs(const short* __restrict__ xn,
                                               const short* __restrict__ w1p,
                                               const short* __restrict__ w2p,
                                               float* __restrict__ scores,
                                               float2* __restrict__ part2) {
  __shared__ __align__(16) short hs[4][2][16 * 64];
  __shared__ float2 stats[4][64];
  const int tid = threadIdx.x, wave = tid >> 6, lane = tid & 63;
  const int l15 = lane & 15, g2 = lane >> 4;
  {  // zero both per-wave buffers (pad cols 48..63 must be non-NaN)
    uint* hz = (uint*)hs[wave];
    for (int i = lane; i < 1024; i += 64) hz[i] = 0u;
  }
  const int row0 = blockIdx.x * 64 + wave * 16;
  f32x4 acc[4];
#pragma unroll
  for (int t = 0; t < 4; ++t) acc[t] = (f32x4){0.f, 0.f, 0.f, 0.f};
  const short* xrow = xn + (size_t)(row0 + l15) * 768;
  const int lo8 = lane * 8;

  short8 bx0 = *(const short8*)(xrow + g2 * 8);
  short8 bx1 = *(const short8*)(xrow + 32 + g2 * 8);
#pragma unroll 2
  for (int g = 0; g < 16; ++g) {
    const int gn = (g < 15) ? g + 1 : 15;
    short8 nbx0 = *(const short8*)(xrow + gn * 48 + g2 * 8);
    short8 nbx1 = *(const short8*)(xrow + gn * 48 + 32 + g2 * 8);
    short* hw = hs[wave][g & 1];
    const short* w1g = w1p + g * 3072;
#pragma unroll
    for (int ot = 0; ot < 3; ++ot) {
      short8 a0 = *(const short8*)(w1g + (ot * 2 + 0) * 512 + lo8);
      short8 a1 = *(const short8*)(w1g + (ot * 2 + 1) * 512 + lo8);
      f32x4 h = (f32x4){0.f, 0.f, 0.f, 0.f};
      h = mfma16(a0, bx0, h);
      h = mfma16(a1, bx1, h);
      uint lo = (uint)f2bits(fmaxf(h[0], 0.f)) | ((uint)f2bits(fmaxf(h[1], 0.f)) << 16);
      uint hi = (uint)f2bits(fmaxf(h[2], 0.f)) | ((uint)f2bits(fmaxf(h[3], 0.f)) << 16);
      *(uint2*)&hw[swz(l15, ot * 16 + g2 * 4)] = make_uint2(lo, hi);
    }
    short8 hb0 = *(const short8*)&hw[swz(l15, g2 * 8)];
    short8 hb1 = *(const short8*)&hw[swz(l15, 32 + g2 * 8)];
    const short* w2g = w2p + g * 4096;
#pragma unroll
    for (int tt = 0; tt < 4; ++tt) {
      short8 a0 = *(const short8*)(w2g + (tt * 2 + 0) * 512 + lo8);
      short8 a1 = *(const short8*)(w2g + (tt * 2 + 1) * 512 + lo8);
      acc[tt] = mfma16(a0, hb0, acc[tt]);
      acc[tt] = mfma16(a1, hb1, acc[tt]);
    }
    bx0 = nbx0; bx1 = nbx1;
  }
#pragma unroll
  for (int tt = 0; tt < 4; ++tt)
#pragma unroll
    for (int r = 0; r < 4; ++r)
      scores[(size_t)(tt * 16 + g2 * 4 + r) * N + row0 + l15] = acc[tt][r];

  // ---- softmax partials for this block's 64 columns -----------------------
#pragma unroll
  for (int tt = 0; tt < 4; ++tt) {
#pragma unroll
    for (int r = 0; r < 4; ++r) {
      float v = acc[tt][r];
      float m = v;
#pragma unroll
      for (int o = 1; o < 16; o <<= 1) m = fmaxf(m, __shfl_xor(m, o, 64));
      float l = __expf(v - m);
#pragma unroll
      for (int o = 1; o < 16; o <<= 1) l += __shfl_xor(l, o, 64);
      if (l15 == 0) stats[wave][tt * 16 + g2 * 4 + r] = make_float2(m, l);
    }
  }
  __syncthreads();
  if (tid < 64) {
    float2 a = stats[0][tid], b = stats[1][tid];
    float M1 = fmaxf(a.x, b.x), L1 = a.y * __expf(a.x - M1) + b.y * __expf(b.x - M1);
    float2 c = stats[2][tid], d = stats[3][tid];
    float M2 = fmaxf(c.x, d.x), L2 = c.y * __expf(c.x - M2) + d.y * __expf(d.x - M2);
    float M = fmaxf(M1, M2), L = L1 * __expf(M1 - M) + L2 * __expf(M2 - M);
    part2[(size_t)tid * 1024 + blockIdx.x] = make_float2(M, L);
  }
}

// ---------------------------------------------------------------------------
// K4: merge 1024 per-block partials per t -> Mv[t], Li[t]=1/L. 64 blocks.
// ---------------------------------------------------------------------------
__global__ __launch_bounds__(256) void k_merge(const float2* __restrict__ part2,
                                               float* __restrict__ Mv,
                                               float* __restrict__ Li) {
  const int t = blockIdx.x, tid = threadIdx.x;
  float M = -1e30f, L = 0.f;
  for (int i = tid; i < 1024; i += 256) {
    float2 p = part2[(size_t)t * 1024 + i];
    float Mx = fmaxf(M, p.x);
    L = L * __expf(M - Mx) + p.y * __expf(p.x - Mx); M = Mx;
  }
#pragma unroll
  for (int o = 32; o > 0; o >>= 1) {
    float m2 = __shfl_xor(M, o, 64), l2 = __shfl_xor(L, o, 64);
    float Mx = fmaxf(M, m2);
    L = L * __expf(M - Mx) + l2 * __expf(m2 - Mx); M = Mx;
  }
  __shared__ float sm[4], sl[4];
  const int wave = tid >> 6, lane = tid & 63;
  if (lane == 0) { sm[wave] = M; sl[wave] = L; }
  __syncthreads();
  if (tid == 0) {
    float Mm = sm[0], Ll = sl[0];
    for (int w = 1; w < 4; w++) {
      float Mx = fmaxf(Mm, sm[w]);
      Ll = Ll * __expf(Mm - Mx) + sl[w] * __expf(sm[w] - Mx); Mm = Mx;
    }
    Mv[t] = Mm; Li[t] = 1.f / Ll;
  }
}

// ---------------------------------------------------------------------------
// K7 (MFMA): fused softmax-apply + sel write + out GEMM.
// Conv waves (gq,ntq) fill featT[2] in LDS; og waves (tt,chalf) read raw
// scores, compute p = exp(s-M)*Li on the fly, write fp32 sel (chalf==0),
// pack bf16 A-frag, MFMA vs featT. 1 barrier/iter; register prefetch.
// ---------------------------------------------------------------------------
__global__ __launch_bounds__(512, 4) void k_og(const short* __restrict__ xn,
                                               const short* __restrict__ wfp,
                                               const float* __restrict__ scores,
                                               const float* __restrict__ Mv,
                                               const float* __restrict__ Li,
                                               const int* __restrict__ ntokp,
                                               float* __restrict__ sel,
                                               ushort* __restrict__ out_part) {
  __shared__ __align__(16) short ft[2][192 * 64];  // 48 KB
  const int tid = threadIdx.x, wave = tid >> 6, lane = tid & 63;
  const int l15 = lane & 15, g2 = lane >> 4;
  const int cb = blockIdx.y, nb = blockIdx.x;
  const int ntok = *ntokp;
  const int gq = wave >> 1, ntq = wave & 1;   // conv role
  const int tt = wave >> 1, chalf = wave & 1; // og role
  const bool act = (tt * 16) < ntok;
  const int tmy = tt * 16 + l15;
  const bool on = tmy < ntok;
  const float M = Mv[tmy], LI = Li[tmy];
  // wf B-fragments (ns-invariant, in regs)
  short8 wb0[3], wb1[3];
  {
    const short* wb = wfp + (size_t)(cb * 4 + gq) * 3072 + lane * 8;
#pragma unroll
    for (int ot = 0; ot < 3; ++ot) {
      wb0[ot] = *(const short8*)(wb + (ot * 2 + 0) * 512);
      wb1[ot] = *(const short8*)(wb + (ot * 2 + 1) * 512);
    }
  }
  f32x4 acc[6];
#pragma unroll
  for (int k = 0; k < 6; ++k) acc[k] = (f32x4){0.f, 0.f, 0.f, 0.f};

  const short* xr0 = xn + (size_t)(nb * 512 + ntq * 16 + l15) * 768 + (cb * 4 + gq) * 48;
  const float* sr0 = scores + (size_t)tmy * N + nb * 512 + g2 * 8;
  float* so0 = sel + (size_t)tmy * N + nb * 512 + g2 * 8;

  short8 bx0 = *(const short8*)(xr0 + g2 * 8);
  short8 bx1 = *(const short8*)(xr0 + 32 + g2 * 8);
  short8 ps = {};
  short8 nx0 = bx0, nx1 = bx1, nps = ps;

  for (int ns = 0; ns <= 16; ++ns) {
    if (ns < 16) {
      // prefetch next-iter xn (consumed after the barrier below)
      const int nsn = (ns < 15) ? ns + 1 : 15;
      nx0 = *(const short8*)(xr0 + nsn * 24576 + g2 * 8);
      nx1 = *(const short8*)(xr0 + nsn * 24576 + 32 + g2 * 8);
      // softmax-apply for chunk ns (consumed by og phase at iter ns+1)
      float4 s0 = *(const float4*)(sr0 + ns * 32);
      float4 s1 = *(const float4*)(sr0 + ns * 32 + 4);
      float4 e0, e1;
      e0.x = on ? __expf(s0.x - M) * LI : 0.f;
      e0.y = on ? __expf(s0.y - M) * LI : 0.f;
      e0.z = on ? __expf(s0.z - M) * LI : 0.f;
      e0.w = on ? __expf(s0.w - M) * LI : 0.f;
      e1.x = on ? __expf(s1.x - M) * LI : 0.f;
      e1.y = on ? __expf(s1.y - M) * LI : 0.f;
      e1.z = on ? __expf(s1.z - M) * LI : 0.f;
      e1.w = on ? __expf(s1.w - M) * LI : 0.f;
      if (chalf == 0) {  // one writer per t-row (both halves compute same e)
        *(float4*)(so0 + ns * 32) = e0;
        *(float4*)(so0 + ns * 32 + 4) = e1;
      }
      nps[0] = (short)f2bits(e0.x); nps[1] = (short)f2bits(e0.y);
      nps[2] = (short)f2bits(e0.z); nps[3] = (short)f2bits(e0.w);
      nps[4] = (short)f2bits(e1.x); nps[5] = (short)f2bits(e1.y);
      nps[6] = (short)f2bits(e1.z); nps[7] = (short)f2bits(e1.w);
      // conv: D[col=c(l15), row=n(g2*4+r)] -> ft[ns&1], contiguous uint2 write
      short* f = ft[ns & 1];
#pragma unroll
      for (int ot = 0; ot < 3; ++ot) {
        f32x4 d = (f32x4){0.f, 0.f, 0.f, 0.f};
        d = mfma16(bx0, wb0[ot], d);
        d = mfma16(bx1, wb1[ot], d);
        int c = gq * 48 + ot * 16 + l15;
        uint lo = (uint)f2bits(d[0]) | ((uint)f2bits(d[1]) << 16);
        uint hi = (uint)f2bits(d[2]) | ((uint)f2bits(d[3]) << 16);
        *(uint2*)&f[c * 64 + ((ntq * 16 + g2 * 4) ^ ((c & 7) << 3))] = make_uint2(lo, hi);
      }
    }
    if (ns >= 1 && act) {
      const short* f = ft[(ns - 1) & 1];
#pragma unroll
      for (int ct = 0; ct < 6; ++ct) {
        int c = (chalf * 6 + ct) * 16 + l15;
        short8 fb = *(const short8*)&f[c * 64 + ((g2 * 8) ^ ((c & 7) << 3))];
        acc[ct] = mfma16(ps, fb, acc[ct]);
      }
    }
    __syncthreads();
    bx0 = nx0; bx1 = nx1; ps = nps;
  }
#pragma unroll
  for (int ct = 0; ct < 6; ++ct)
#pragma unroll
    for (int r = 0; r < 4; ++r) {
      int t = tt * 16 + g2 * 4 + r;
      int c = cb * 192 + (chalf * 6 + ct) * 16 + l15;
      out_part[(size_t)nb * (64 * 768) + t * 768 + c] = f2bits(acc[ct][r]);
    }
}

// ---------------------------------------------------------------------------
// K8: fused reduce(128 nb partials) + final LayerNorm + mask. 64 blocks (one
// per t), 192 threads (4 c each), uint2 (4xbf16) loads.
// ---------------------------------------------------------------------------
__global__ __launch_bounds__(192) void k_fin(const ushort* __restrict__ out_part,
                                             const float* __restrict__ ng,
                                             const float* __restrict__ nb_,
                                             const int* __restrict__ ntokp,
                                             float* __restrict__ outp) {
  const int t = blockIdx.x, tid = threadIdx.x;
  const int wave = tid >> 6, lane = tid & 63;
  const int c4 = tid * 4;
  float4 s = make_float4(0.f, 0.f, 0.f, 0.f);
  const ushort* base = out_part + t * 768 + c4;
  for (int nbk = 0; nbk < 128; ++nbk) {
    uint2 v = *(const uint2*)(base + (size_t)nbk * 49152);
    s.x += bits2f((ushort)(v.x & 0xffff)); s.y += bits2f((ushort)(v.x >> 16));
    s.z += bits2f((ushort)(v.y & 0xffff)); s.w += bits2f((ushort)(v.y >> 16));
  }
  float ss = s.x + s.y + s.z + s.w;
  float qq = s.x * s.x + s.y * s.y + s.z * s.z + s.w * s.w;
  ss = wredsum(ss); qq = wredsum(qq);
  __shared__ float sm[3], sq[3];
  if (lane == 0) { sm[wave] = ss; sq[wave] = qq; }
  __syncthreads();
  const float S = sm[0] + sm[1] + sm[2], Q = sq[0] + sq[1] + sq[2];
  const float mu = S * (1.f / C);
  const float rs = rsqrtf(Q * (1.f / C) - mu * mu + 1e-5f);
  const bool on = t < *ntokp;
  float4 g = *(const float4*)(ng + c4), b = *(const float4*)(nb_ + c4);
  float4 y;
  y.x = on ? (s.x - mu) * rs * g.x + b.x : 0.f;
  y.y = on ? (s.y - mu) * rs * g.y + b.y : 0.f;
  y.z = on ? (s.z - mu) * rs * g.z + b.z : 0.f;
  y.w = on ? (s.w - mu) * rs * g.w + b.w : 0.f;
  *(float4*)(outp + t * 768 + c4) = y;
}

// ---------------------------------------------------------------------------
extern "C" void kernel_launch(void* const* d_in, const int* in_sizes, int n_in,
                              void* d_out, int out_size, void* d_ws, size_t ws_size,
                              hipStream_t stream) {
  const float* x  = (const float*)d_in[0];
  const float* tg = (const float*)d_in[1];
  const float* tb = (const float*)d_in[2];
  const float* w1 = (const float*)d_in[3];
  const float* w2 = (const float*)d_in[4];
  const float* wf = (const float*)d_in[5];
  const float* pw = (const float*)d_in[6];
  const float* pb = (const float*)d_in[7];
  const float* ng = (const float*)d_in[8];
  const float* nb = (const float*)d_in[9];

  char* ws = (char*)d_ws;
  float*  pooled = (float*)(ws + 0);           // 3,072 B
  int*    ntok   = (int*)(ws + 8704);
  float*  Mv     = (float*)(ws + 8960);        // 256 B
  float*  Li     = (float*)(ws + 9216);        // 256 B
  short*  w1p    = (short*)(ws + 16384);       //  98,304 B
  short*  w2p    = (short*)(ws + 114688);      // 131,072 B
  short*  wfp    = (short*)(ws + 245760);      //  98,304 B
  float2* part2  = (float2*)(ws + 344064);     // 524,288 B -> ends 868,352
  short*  xn     = (short*)(ws + 868352);      // 100,663,296 B -> ends 101,531,648
  float*  scores = (float*)(ws + 101531648);   // 16,777,216 B -> ends 118,308,864
  ushort* opart  = (ushort*)(ws + 118308864);  // 12,582,912 B -> ends 130,891,776

  float* sel  = (float*)d_out;
  float* outp = (float*)d_out + (size_t)T * N;

  (void)hipMemsetAsync(pooled, 0, C * sizeof(float), stream);

  k_wprep <<<640, 256, 0, stream>>>(w1, w2, wf, w1p, w2p, wfp);
  k_ln    <<<1024, 256, 0, stream>>>((const float4*)x, (const float4*)tg, (const float4*)tb,
                                     (uint2*)xn, pooled);
  k_pool  <<<1, 256, 0, stream>>>(pooled, pw, pb, ntok);
  k_cs    <<<1024, 256, 0, stream>>>(xn, w1p, w2p, scores, part2);
  k_merge <<<64, 256, 0, stream>>>(part2, Mv, Li);
  k_og    <<<dim3(128, 4), 512, 0, stream>>>(xn, wfp, scores, Mv, Li, ntok, sel, opart);
  k_fin   <<<64, 192, 0, stream>>>(opart, ng, nb, ntok, outp);
}

// Round 8
// 444.080 us; speedup vs baseline: 1.0041x; 1.0041x over previous
//
#include <hip/hip_runtime.h>
#include <hip/hip_bf16.h>

#define DEV __device__ __forceinline__

constexpr int N = 65536;
constexpr int C = 768;
constexpr int T = 64;

using bf16 = __hip_bfloat16;
using short8 = __attribute__((ext_vector_type(8))) short;
using f32x4  = __attribute__((ext_vector_type(4))) float;

DEV ushort f2bits(float v) { union { __hip_bfloat16 h; ushort u; } x; x.h = __float2bfloat16(v); return x.u; }
DEV float bits2f(ushort b) { union { uint u; float f; } x; x.u = ((uint)b) << 16; return x.f; }
DEV f32x4 mfma16(short8 a, short8 b, f32x4 c) { return __builtin_amdgcn_mfma_f32_16x16x32_bf16(a, b, c, 0, 0, 0); }
// XOR swizzle: 16B-unit permutation within a 128B (64-short) row. Bijective per row.
DEV int swz(int row, int col) { return row * 64 + (col ^ ((row & 7) << 3)); }

DEV float wredsum(float v) {
#pragma unroll
  for (int o = 32; o > 0; o >>= 1) v += __shfl_xor(v, o, 64);
  return v;
}

// ---------------------------------------------------------------------------
// K0: pack w1/w2/wf into MFMA-fragment-ordered bf16 arrays, zero-padded K 48->64.
// frag f = (g*NT + tile)*2 + ktile; element [f*512 + lane*8 + j]
//   = W[row = tile*16 + (lane&15)][k = ktile*32 + ((lane>>4)&3)*8 + j]
// ---------------------------------------------------------------------------
__global__ __launch_bounds__(256) void k_wprep(const float* __restrict__ w1,
                                               const float* __restrict__ w2,
                                               const float* __restrict__ wf,
                                               short* __restrict__ w1p,
                                               short* __restrict__ w2p,
                                               short* __restrict__ wfp) {
  const int b = blockIdx.x, tid = threadIdx.x;
  if (b < 192) {            // w1p: 16 g * 3 ot * 2 kt * 512 = 49152
    int idx = b * 256 + tid;
    int j = idx & 7, lane = (idx >> 3) & 63, u = idx >> 9;
    int kt = u & 1, v = u >> 1, ot = v % 3, g = v / 3;
    int o = ot * 16 + (lane & 15), k = kt * 32 + ((lane >> 4) & 3) * 8 + j;
    w1p[idx] = (k < 48) ? (short)f2bits(w1[g * 2304 + o * 48 + k]) : (short)0;
  } else if (b < 448) {     // w2p: 16 g * 4 tt * 2 kt * 512 = 65536
    int idx = (b - 192) * 256 + tid;
    int j = idx & 7, lane = (idx >> 3) & 63, u = idx >> 9;
    int kt = u & 1, v = u >> 1, tt = v & 3, g = v >> 2;
    int t = tt * 16 + (lane & 15), k = kt * 32 + ((lane >> 4) & 3) * 8 + j;
    w2p[idx] = (k < 48) ? (short)f2bits(w2[t * 768 + g * 48 + k]) : (short)0;
  } else {                  // wfp: like w1p
    int idx = (b - 448) * 256 + tid;
    int j = idx & 7, lane = (idx >> 3) & 63, u = idx >> 9;
    int kt = u & 1, v = u >> 1, ot = v % 3, g = v / 3;
    int o = ot * 16 + (lane & 15), k = kt * 32 + ((lane >> 4) & 3) * 8 + j;
    wfp[idx] = (k < 48) ? (short)f2bits(wf[g * 2304 + o * 48 + k]) : (short)0;
  }
}

// ---------------------------------------------------------------------------
// K1: LayerNorm rows of x -> xn (bf16) + pooled sums. Single-pass moments.
// ---------------------------------------------------------------------------
__global__ __launch_bounds__(256, 4) void k_ln(const float4* __restrict__ x,
                                               const float4* __restrict__ gam,
                                               const float4* __restrict__ bet,
                                               uint2* __restrict__ xn,
                                               float* __restrict__ pooled) {
  const int tid = threadIdx.x, wave = tid >> 6, lane = tid & 63;
  float4 gg[3], bb[3], pool[3];
#pragma unroll
  for (int j = 0; j < 3; j++) {
    gg[j] = gam[lane + 64 * j]; bb[j] = bet[lane + 64 * j];
    pool[j] = make_float4(0.f, 0.f, 0.f, 0.f);
  }
  const int r0 = (blockIdx.x * 4 + wave) * 16;
  for (int r = r0; r < r0 + 16; ++r) {
    const float4* xr = x + (size_t)r * 192;
    float4 v[3]; float s = 0.f, q = 0.f;
#pragma unroll
    for (int j = 0; j < 3; j++) {
      v[j] = xr[lane + 64 * j];
      s += v[j].x + v[j].y + v[j].z + v[j].w;
      q += v[j].x * v[j].x + v[j].y * v[j].y + v[j].z * v[j].z + v[j].w * v[j].w;
    }
    s = wredsum(s); q = wredsum(q);
    const float mu = s * (1.f / C);
    const float rs = rsqrtf(q * (1.f / C) - mu * mu + 1e-5f);
    uint2* xo = xn + (size_t)r * 192;
#pragma unroll
    for (int j = 0; j < 3; j++) {
      float y0 = (v[j].x - mu) * rs * gg[j].x + bb[j].x;
      float y1 = (v[j].y - mu) * rs * gg[j].y + bb[j].y;
      float y2 = (v[j].z - mu) * rs * gg[j].z + bb[j].z;
      float y3 = (v[j].w - mu) * rs * gg[j].w + bb[j].w;
      pool[j].x += y0; pool[j].y += y1; pool[j].z += y2; pool[j].w += y3;
      xo[lane + 64 * j] = make_uint2((uint)f2bits(y0) | ((uint)f2bits(y1) << 16),
                                     (uint)f2bits(y2) | ((uint)f2bits(y3) << 16));
    }
  }
  __shared__ float lp[4][C];
#pragma unroll
  for (int j = 0; j < 3; j++) {
    int base = (lane + 64 * j) * 4;
    lp[wave][base] = pool[j].x; lp[wave][base + 1] = pool[j].y;
    lp[wave][base + 2] = pool[j].z; lp[wave][base + 3] = pool[j].w;
  }
  __syncthreads();
  for (int c = tid; c < C; c += 256)
    atomicAdd(&pooled[c], lp[0][c] + lp[1][c] + lp[2][c] + lp[3][c]);
}

// ---------------------------------------------------------------------------
// K2: pooled -> ratio -> num_tokens
// ---------------------------------------------------------------------------
__global__ __launch_bounds__(256) void k_pool(const float* __restrict__ pooled,
                                              const float* __restrict__ pw,
                                              const float* __restrict__ pb,
                                              int* __restrict__ ntok) {
  const int tid = threadIdx.x, wave = tid >> 6, lane = tid & 63;
  float a = 0.f;
  for (int c = tid; c < C; c += 256) a += pooled[c] * (1.f / N) * pw[c];
  a = wredsum(a);
  __shared__ float red[4];
  if (lane == 0) red[wave] = a;
  __syncthreads();
  if (tid == 0) {
    float d = red[0] + red[1] + red[2] + red[3] + pb[0];
    float ratio = 1.f / (1.f + expf(-d));
    int nt = (int)floorf(ratio * 64.f);
    nt = nt < 0 ? 0 : (nt > 64 ? 64 : nt);
    *ntok = nt;
  }
}

// ---------------------------------------------------------------------------
// K3 (MFMA): fused grouped conv1 + ReLU + scores GEMM + per-block softmax
// partials. Per-wave double-buffered h (g&1); fragment-ordered weights from
// global (L1/L2-hot). Epilogue: in-block (m, sumexp) per t -> part2[t][blk].
// ---------------------------------------------------------------------------
__global__ __launch_bounds__(256, 4) void k_cs(const short* __restrict__ xn,
                                               const short* __restrict__ w1p,
                                               const short* __restrict__ w2p,
                                               float* __restrict__ scores,
                                               float2* __restrict__ part2) {
  __shared__ __align__(16) short hs[4][2][16 * 64];
  __shared__ float2 stats[4][64];
  const int tid = threadIdx.x, wave = tid >> 6, lane = tid & 63;
  const int l15 = lane & 15, g2 = lane >> 4;
  {  // zero both per-wave buffers (pad cols 48..63 must be non-NaN)
    uint* hz = (uint*)hs[wave];
    for (int i = lane; i < 1024; i += 64) hz[i] = 0u;
  }
  const int row0 = blockIdx.x * 64 + wave * 16;
  f32x4 acc[4];
#pragma unroll
  for (int t = 0; t < 4; ++t) acc[t] = (f32x4){0.f, 0.f, 0.f, 0.f};
  const short* xrow = xn + (size_t)(row0 + l15) * 768;
  const int lo8 = lane * 8;

  short8 bx0 = *(const short8*)(xrow + g2 * 8);
  short8 bx1 = *(const short8*)(xrow + 32 + g2 * 8);
#pragma unroll 2
  for (int g = 0; g < 16; ++g) {
    const int gn = (g < 15) ? g + 1 : 15;
    short8 nbx0 = *(const short8*)(xrow + gn * 48 + g2 * 8);
    short8 nbx1 = *(const short8*)(xrow + gn * 48 + 32 + g2 * 8);
    short* hw = hs[wave][g & 1];
    const short* w1g = w1p + g * 3072;
#pragma unroll
    for (int ot = 0; ot < 3; ++ot) {
      short8 a0 = *(const short8*)(w1g + (ot * 2 + 0) * 512 + lo8);
      short8 a1 = *(const short8*)(w1g + (ot * 2 + 1) * 512 + lo8);
      f32x4 h = (f32x4){0.f, 0.f, 0.f, 0.f};
      h = mfma16(a0, bx0, h);
      h = mfma16(a1, bx1, h);
      uint lo = (uint)f2bits(fmaxf(h[0], 0.f)) | ((uint)f2bits(fmaxf(h[1], 0.f)) << 16);
      uint hi = (uint)f2bits(fmaxf(h[2], 0.f)) | ((uint)f2bits(fmaxf(h[3], 0.f)) << 16);
      *(uint2*)&hw[swz(l15, ot * 16 + g2 * 4)] = make_uint2(lo, hi);
    }
    short8 hb0 = *(const short8*)&hw[swz(l15, g2 * 8)];
    short8 hb1 = *(const short8*)&hw[swz(l15, 32 + g2 * 8)];
    const short* w2g = w2p + g * 4096;
#pragma unroll
    for (int tt = 0; tt < 4; ++tt) {
      short8 a0 = *(const short8*)(w2g + (tt * 2 + 0) * 512 + lo8);
      short8 a1 = *(const short8*)(w2g + (tt * 2 + 1) * 512 + lo8);
      acc[tt] = mfma16(a0, hb0, acc[tt]);
      acc[tt] = mfma16(a1, hb1, acc[tt]);
    }
    bx0 = nbx0; bx1 = nbx1;
  }
#pragma unroll
  for (int tt = 0; tt < 4; ++tt)
#pragma unroll
    for (int r = 0; r < 4; ++r)
      scores[(size_t)(tt * 16 + g2 * 4 + r) * N + row0 + l15] = acc[tt][r];

  // ---- softmax partials for this block's 64 columns -----------------------
#pragma unroll
  for (int tt = 0; tt < 4; ++tt) {
#pragma unroll
    for (int r = 0; r < 4; ++r) {
      float v = acc[tt][r];
      float m = v;
#pragma unroll
      for (int o = 1; o < 16; o <<= 1) m = fmaxf(m, __shfl_xor(m, o, 64));
      float l = __expf(v - m);
#pragma unroll
      for (int o = 1; o < 16; o <<= 1) l += __shfl_xor(l, o, 64);
      if (l15 == 0) stats[wave][tt * 16 + g2 * 4 + r] = make_float2(m, l);
    }
  }
  __syncthreads();
  if (tid < 64) {
    float2 a = stats[0][tid], b = stats[1][tid];
    float M1 = fmaxf(a.x, b.x), L1 = a.y * __expf(a.x - M1) + b.y * __expf(b.x - M1);
    float2 c = stats[2][tid], d = stats[3][tid];
    float M2 = fmaxf(c.x, d.x), L2 = c.y * __expf(c.x - M2) + d.y * __expf(d.x - M2);
    float M = fmaxf(M1, M2), L = L1 * __expf(M1 - M) + L2 * __expf(M2 - M);
    part2[(size_t)tid * 1024 + blockIdx.x] = make_float2(M, L);
  }
}

// ---------------------------------------------------------------------------
// K4: merge 1024 per-block partials per t -> Mv[t], Li[t]=1/L. 64 blocks.
// ---------------------------------------------------------------------------
__global__ __launch_bounds__(256) void k_merge(const float2* __restrict__ part2,
                                               float* __restrict__ Mv,
                                               float* __restrict__ Li) {
  const int t = blockIdx.x, tid = threadIdx.x;
  float M = -1e30f, L = 0.f;
  for (int i = tid; i < 1024; i += 256) {
    float2 p = part2[(size_t)t * 1024 + i];
    float Mx = fmaxf(M, p.x);
    L = L * __expf(M - Mx) + p.y * __expf(p.x - Mx); M = Mx;
  }
#pragma unroll
  for (int o = 32; o > 0; o >>= 1) {
    float m2 = __shfl_xor(M, o, 64), l2 = __shfl_xor(L, o, 64);
    float Mx = fmaxf(M, m2);
    L = L * __expf(M - Mx) + l2 * __expf(m2 - Mx); M = Mx;
  }
  __shared__ float sm[4], sl[4];
  const int wave = tid >> 6, lane = tid & 63;
  if (lane == 0) { sm[wave] = M; sl[wave] = L; }
  __syncthreads();
  if (tid == 0) {
    float Mm = sm[0], Ll = sl[0];
    for (int w = 1; w < 4; w++) {
      float Mx = fmaxf(Mm, sm[w]);
      Ll = Ll * __expf(Mm - Mx) + sl[w] * __expf(sm[w] - Mx); Mm = Mx;
    }
    Mv[t] = Mm; Li[t] = 1.f / Ll;
  }
}

// ---------------------------------------------------------------------------
// K7 (MFMA): fused softmax-apply + sel write + out GEMM.
// Conv waves (gq,ntq) fill featT[2] in LDS; og waves (tt,chalf) read raw
// scores, compute p = exp(s-M)*Li on the fly, write fp32 sel (cb==0 &&
// chalf==0 only), pack bf16 A-frag, MFMA vs featT. wf kt0-frags live in LDS
// (12 KB, lane-linear ds_read_b128) to keep VGPR <= 128 at (512,4).
// ---------------------------------------------------------------------------
__global__ __launch_bounds__(512, 4) void k_og(const short* __restrict__ xn,
                                               const short* __restrict__ wfp,
                                               const float* __restrict__ scores,
                                               const float* __restrict__ Mv,
                                               const float* __restrict__ Li,
                                               const int* __restrict__ ntokp,
                                               float* __restrict__ sel,
                                               ushort* __restrict__ out_part) {
  __shared__ __align__(16) short ft[2][192 * 64];   // 48 KB
  __shared__ __align__(16) short wfs[4 * 3 * 512];  // 12 KB (kt=0 frags)
  const int tid = threadIdx.x, wave = tid >> 6, lane = tid & 63;
  const int l15 = lane & 15, g2 = lane >> 4;
  const int cb = blockIdx.y, nb = blockIdx.x;
  const int ntok = *ntokp;
  const int gq = wave >> 1, ntq = wave & 1;   // conv role
  const int tt = wave >> 1, chalf = wave & 1; // og role
  const bool act = (tt * 16) < ntok;
  const int tmy = tt * 16 + l15;
  const bool on = tmy < ntok;
  const float M = Mv[tmy], LI = Li[tmy];
  const int lo8 = lane * 8;
  // stage kt=0 wf fragments to LDS: wfs[(g*3+ot)*512 + e] = wfp[(cb*4+g)*3072 + ot*1024 + e]
  for (int i = tid; i < 1536; i += 512) {  // uint2 = 4 shorts
    int frag = i >> 7, e4 = i & 127;
    int g = frag / 3, ot = frag - g * 3;
    ((uint2*)wfs)[i] = *(const uint2*)(wfp + (size_t)(cb * 4 + g) * 3072 + ot * 1024 + e4 * 4);
  }
  // kt=1 wf fragments stay in registers (ns-invariant)
  short8 wb1[3];
  {
    const short* wb = wfp + (size_t)(cb * 4 + gq) * 3072 + lo8;
#pragma unroll
    for (int ot = 0; ot < 3; ++ot) wb1[ot] = *(const short8*)(wb + (ot * 2 + 1) * 512);
  }
  f32x4 acc[6];
#pragma unroll
  for (int k = 0; k < 6; ++k) acc[k] = (f32x4){0.f, 0.f, 0.f, 0.f};

  const short* xr0 = xn + (size_t)(nb * 512 + ntq * 16 + l15) * 768 + (cb * 4 + gq) * 48;
  const float* sr0 = scores + (size_t)tmy * N + nb * 512 + g2 * 8;
  float* so0 = sel + (size_t)tmy * N + nb * 512 + g2 * 8;
  const bool selw = (chalf == 0) && (cb == 0);

  short8 bx0 = *(const short8*)(xr0 + g2 * 8);
  short8 bx1 = *(const short8*)(xr0 + 32 + g2 * 8);
  short8 ps = {};
  short8 nx0 = bx0, nx1 = bx1, nps = ps;
  __syncthreads();  // wfs staged

  for (int ns = 0; ns <= 16; ++ns) {
    if (ns < 16) {
      // prefetch next-iter xn (consumed after the barrier below)
      const int nsn = (ns < 15) ? ns + 1 : 15;
      nx0 = *(const short8*)(xr0 + nsn * 24576 + g2 * 8);
      nx1 = *(const short8*)(xr0 + nsn * 24576 + 32 + g2 * 8);
      // softmax-apply for chunk ns (consumed by og phase at iter ns+1)
      float4 s0 = *(const float4*)(sr0 + ns * 32);
      float4 s1 = *(const float4*)(sr0 + ns * 32 + 4);
      float4 e0, e1;
      e0.x = on ? __expf(s0.x - M) * LI : 0.f;
      e0.y = on ? __expf(s0.y - M) * LI : 0.f;
      e0.z = on ? __expf(s0.z - M) * LI : 0.f;
      e0.w = on ? __expf(s0.w - M) * LI : 0.f;
      e1.x = on ? __expf(s1.x - M) * LI : 0.f;
      e1.y = on ? __expf(s1.y - M) * LI : 0.f;
      e1.z = on ? __expf(s1.z - M) * LI : 0.f;
      e1.w = on ? __expf(s1.w - M) * LI : 0.f;
      if (selw) {
        *(float4*)(so0 + ns * 32) = e0;
        *(float4*)(so0 + ns * 32 + 4) = e1;
      }
      nps[0] = (short)f2bits(e0.x); nps[1] = (short)f2bits(e0.y);
      nps[2] = (short)f2bits(e0.z); nps[3] = (short)f2bits(e0.w);
      nps[4] = (short)f2bits(e1.x); nps[5] = (short)f2bits(e1.y);
      nps[6] = (short)f2bits(e1.z); nps[7] = (short)f2bits(e1.w);
      // conv: D[col=c(l15), row=n(g2*4+r)] -> ft[ns&1], contiguous uint2 write
      short* f = ft[ns & 1];
#pragma unroll
      for (int ot = 0; ot < 3; ++ot) {
        short8 a0 = *(const short8*)&wfs[(gq * 3 + ot) * 512 + lo8];
        f32x4 d = (f32x4){0.f, 0.f, 0.f, 0.f};
        d = mfma16(bx0, a0, d);
        d = mfma16(bx1, wb1[ot], d);
        int c = gq * 48 + ot * 16 + l15;
        uint lo = (uint)f2bits(d[0]) | ((uint)f2bits(d[1]) << 16);
        uint hi = (uint)f2bits(d[2]) | ((uint)f2bits(d[3]) << 16);
        *(uint2*)&f[c * 64 + ((ntq * 16 + g2 * 4) ^ ((c & 7) << 3))] = make_uint2(lo, hi);
      }
    }
    if (ns >= 1 && act) {
      const short* f = ft[(ns - 1) & 1];
#pragma unroll
      for (int ct = 0; ct < 6; ++ct) {
        int c = (chalf * 6 + ct) * 16 + l15;
        short8 fb = *(const short8*)&f[c * 64 + ((g2 * 8) ^ ((c & 7) << 3))];
        acc[ct] = mfma16(ps, fb, acc[ct]);
      }
    }
    __syncthreads();
    bx0 = nx0; bx1 = nx1; ps = nps;
  }
#pragma unroll
  for (int ct = 0; ct < 6; ++ct)
#pragma unroll
    for (int r = 0; r < 4; ++r) {
      int t = tt * 16 + g2 * 4 + r;
      int c = cb * 192 + (chalf * 6 + ct) * 16 + l15;
      out_part[(size_t)nb * (64 * 768) + t * 768 + c] = f2bits(acc[ct][r]);
    }
}

// ---------------------------------------------------------------------------
// K8: fused reduce(128 nb partials) + final LayerNorm + mask. 64 blocks (one
// per t), 192 threads (4 c each), uint2 (4xbf16) loads.
// ---------------------------------------------------------------------------
__global__ __launch_bounds__(192) void k_fin(const ushort* __restrict__ out_part,
                                             const float* __restrict__ ng,
                                             const float* __restrict__ nb_,
                                             const int* __restrict__ ntokp,
                                             float* __restrict__ outp) {
  const int t = blockIdx.x, tid = threadIdx.x;
  const int wave = tid >> 6, lane = tid & 63;
  const int c4 = tid * 4;
  float4 s = make_float4(0.f, 0.f, 0.f, 0.f);
  const ushort* base = out_part + t * 768 + c4;
  for (int nbk = 0; nbk < 128; ++nbk) {
    uint2 v = *(const uint2*)(base + (size_t)nbk * 49152);
    s.x += bits2f((ushort)(v.x & 0xffff)); s.y += bits2f((ushort)(v.x >> 16));
    s.z += bits2f((ushort)(v.y & 0xffff)); s.w += bits2f((ushort)(v.y >> 16));
  }
  float ss = s.x + s.y + s.z + s.w;
  float qq = s.x * s.x + s.y * s.y + s.z * s.z + s.w * s.w;
  ss = wredsum(ss); qq = wredsum(qq);
  __shared__ float sm[3], sq[3];
  if (lane == 0) { sm[wave] = ss; sq[wave] = qq; }
  __syncthreads();
  const float S = sm[0] + sm[1] + sm[2], Q = sq[0] + sq[1] + sq[2];
  const float mu = S * (1.f / C);
  const float rs = rsqrtf(Q * (1.f / C) - mu * mu + 1e-5f);
  const bool on = t < *ntokp;
  float4 g = *(const float4*)(ng + c4), b = *(const float4*)(nb_ + c4);
  float4 y;
  y.x = on ? (s.x - mu) * rs * g.x + b.x : 0.f;
  y.y = on ? (s.y - mu) * rs * g.y + b.y : 0.f;
  y.z = on ? (s.z - mu) * rs * g.z + b.z : 0.f;
  y.w = on ? (s.w - mu) * rs * g.w + b.w : 0.f;
  *(float4*)(outp + t * 768 + c4) = y;
}

// ---------------------------------------------------------------------------
extern "C" void kernel_launch(void* const* d_in, const int* in_sizes, int n_in,
                              void* d_out, int out_size, void* d_ws, size_t ws_size,
                              hipStream_t stream) {
  const float* x  = (const float*)d_in[0];
  const float* tg = (const float*)d_in[1];
  const float* tb = (const float*)d_in[2];
  const float* w1 = (const float*)d_in[3];
  const float* w2 = (const float*)d_in[4];
  const float* wf = (const float*)d_in[5];
  const float* pw = (const float*)d_in[6];
  const float* pb = (const float*)d_in[7];
  const float* ng = (const float*)d_in[8];
  const float* nb = (const float*)d_in[9];

  char* ws = (char*)d_ws;
  float*  pooled = (float*)(ws + 0);           // 3,072 B
  int*    ntok   = (int*)(ws + 8704);
  float*  Mv     = (float*)(ws + 8960);        // 256 B
  float*  Li     = (float*)(ws + 9216);        // 256 B
  short*  w1p    = (short*)(ws + 16384);       //  98,304 B
  short*  w2p    = (short*)(ws + 114688);      // 131,072 B
  short*  wfp    = (short*)(ws + 245760);      //  98,304 B
  float2* part2  = (float2*)(ws + 344064);     // 524,288 B -> ends 868,352
  short*  xn     = (short*)(ws + 868352);      // 100,663,296 B -> ends 101,531,648
  float*  scores = (float*)(ws + 101531648);   // 16,777,216 B -> ends 118,308,864
  ushort* opart  = (ushort*)(ws + 118308864);  // 12,582,912 B -> ends 130,891,776

  float* sel  = (float*)d_out;
  float* outp = (float*)d_out + (size_t)T * N;

  (void)hipMemsetAsync(pooled, 0, C * sizeof(float), stream);

  k_wprep <<<640, 256, 0, stream>>>(w1, w2, wf, w1p, w2p, wfp);
  k_ln    <<<1024, 256, 0, stream>>>((const float4*)x, (const float4*)tg, (const float4*)tb,
                                     (uint2*)xn, pooled);
  k_pool  <<<1, 256, 0, stream>>>(pooled, pw, pb, ntok);
  k_cs    <<<1024, 256, 0, stream>>>(xn, w1p, w2p, scores, part2);
  k_merge <<<64, 256, 0, stream>>>(part2, Mv, Li);
  k_og    <<<dim3(128, 4), 512, 0, stream>>>(xn, wfp, scores, Mv, Li, ntok, sel, opart);
  k_fin   <<<64, 192, 0, stream>>>(opart, ng, nb, ntok, outp);
}